// Round 6
// baseline (275.991 us; speedup 1.0000x reference)
//
#include <hip/hip_runtime.h>

// out[i] = image[i*3 + 0] * w[i*16 + 15], i in [0, 4096*4096)
//
// R1 structure (best: 231us) + nontemporal (no-allocate) LOADS:
//   both input streams are read-exactly-once -> L2 allocation is pure
//   overhead; nt hint skips fill/evict machinery. Stores stay regular
//   (NT-store regressed in the R3 bundle).
//   img: 3x dwordx4 contiguous per thread (4 outputs/thread)
//   w:   4x scalar strided (every 64B sector needed regardless)
//   out: 1x dwordx4 per thread
// Traffic floor: 201MB (img) + 1074MB (w sectors) + 67MB (out) = 1.342 GB.

typedef float f32x4 __attribute__((ext_vector_type(4)));

__global__ __launch_bounds__(256) void MyLayer_kernel(
    const f32x4* __restrict__ img4,
    const float* __restrict__ w,
    f32x4*       __restrict__ out4)
{
    const size_t t  = (size_t)blockIdx.x * blockDim.x + threadIdx.x;
    const size_t ib = t * 3;

    const f32x4 a = __builtin_nontemporal_load(&img4[ib + 0]);
    const f32x4 b = __builtin_nontemporal_load(&img4[ib + 1]);
    const f32x4 c = __builtin_nontemporal_load(&img4[ib + 2]);

    const float* wp = w + t * 64 + 15;
    const float w0 = __builtin_nontemporal_load(&wp[0]);
    const float w1 = __builtin_nontemporal_load(&wp[16]);
    const float w2 = __builtin_nontemporal_load(&wp[32]);
    const float w3 = __builtin_nontemporal_load(&wp[48]);

    f32x4 o;
    o.x = a.x * w0;   // (4t+0)*3
    o.y = a.w * w1;   // (4t+1)*3
    o.z = b.z * w2;   // (4t+2)*3
    o.w = c.y * w3;   // (4t+3)*3
    out4[t] = o;
}

extern "C" void kernel_launch(void* const* d_in, const int* in_sizes, int n_in,
                              void* d_out, int out_size, void* d_ws, size_t ws_size,
                              hipStream_t stream)
{
    const float* image = (const float*)d_in[0];  // (4096,4096,3) f32
    const float* w     = (const float*)d_in[1];  // (4096,4096,16) f32
    float*       out   = (float*)d_out;          // (4096,4096) f32

    const int n = 4096 * 4096;
    const int threads = 256;
    const int blocks  = n / 4 / threads;         // 16384, exact

    MyLayer_kernel<<<blocks, threads, 0, stream>>>(
        (const f32x4*)image, w, (f32x4*)out);
}

// Round 7
// 249.317 us; speedup vs baseline: 1.1070x; 1.1070x over previous
//
#include <hip/hip_runtime.h>

// out[i] = image[i*3 + 0] * w[i*16 + 15], i in [0, 4096*4096)
//
// FINAL (best measured: 231.0 us = 5.81 TB/s effective, 92% of the 6.29 TB/s
// dense-copy ceiling). Traffic is irreducible at sector granularity:
//   image (4096,4096,3) f32: ch-0 at 12B stride -> every 64B sector needed
//          -> 201MB. Loaded as 3x dwordx4 contiguous per thread.
//   w (4096,4096,16) f32: ch-15 at 64B stride -> one dword per sector, every
//          sector needed -> 1074MB. Scalar strided loads; each 128B L2 line
//          holds 2 needed dwords, second touch hits L2 (NT-load regressed 19%).
//   out (4096,4096) f32: 67MB, dwordx4 stores.
// Refuted alternatives: 8/thr (240), lane-dense scalar (255), lane-dense w
// via LDS (247), NT loads (276), NT stores (240-bundle).

typedef float f32x4 __attribute__((ext_vector_type(4)));

__global__ __launch_bounds__(256) void MyLayer_kernel(
    const f32x4* __restrict__ img4,
    const float* __restrict__ w,
    f32x4*       __restrict__ out4)
{
    const size_t t  = (size_t)blockIdx.x * blockDim.x + threadIdx.x;
    const size_t ib = t * 3;

    // image bytes [t*48, t*48+48): channel-0 at float positions 0,3,6,9
    const f32x4 a = img4[ib + 0];
    const f32x4 b = img4[ib + 1];
    const f32x4 c = img4[ib + 2];

    // w element (4t+k)*16 + 15; k*64B offsets fold into load immediates
    const float* wp = w + t * 64 + 15;
    const float w0 = wp[0];
    const float w1 = wp[16];
    const float w2 = wp[32];
    const float w3 = wp[48];

    f32x4 o;
    o.x = a.x * w0;   // (4t+0)*3
    o.y = a.w * w1;   // (4t+1)*3
    o.z = b.z * w2;   // (4t+2)*3
    o.w = c.y * w3;   // (4t+3)*3
    out4[t] = o;
}

extern "C" void kernel_launch(void* const* d_in, const int* in_sizes, int n_in,
                              void* d_out, int out_size, void* d_ws, size_t ws_size,
                              hipStream_t stream)
{
    const float* image = (const float*)d_in[0];  // (4096,4096,3) f32
    const float* w     = (const float*)d_in[1];  // (4096,4096,16) f32
    float*       out   = (float*)d_out;          // (4096,4096) f32

    const int n = 4096 * 4096;
    const int threads = 256;
    const int blocks  = n / 4 / threads;         // 16384, exact

    MyLayer_kernel<<<blocks, threads, 0, stream>>>(
        (const f32x4*)image, w, (f32x4*)out);
}